// Round 1
// baseline (402.120 us; speedup 1.0000x reference)
//
#include <hip/hip_runtime.h>
#include <hip/hip_bf16.h>
#include <cstdint>

// VanillaLSTMCell: B=8192, I=H=1024.
// z = [x|h] @ [Wx;Wh]^T + b  (M=8192, N=4096, K=2048), gates i,f,o,g gate-major in N.
// Pipeline: pack(f32->bf16) -> bf16 MFMA GEMM (m97 structure) -> LSTM pointwise.

typedef __bf16 bf16;
typedef __attribute__((ext_vector_type(8))) bf16 bf16x8;
typedef __attribute__((ext_vector_type(4))) bf16 bf16x4;
typedef __attribute__((ext_vector_type(4))) float f32x4;

#define BM 128
#define BN 128
#define BK 32

// ---- async global->LDS helper (16B per lane; LDS dest = wave-uniform base + lane*16) ----
__device__ __forceinline__ void gload_lds16(const void* g, void* l) {
  __builtin_amdgcn_global_load_lds(
      (__attribute__((address_space(1))) void*)(void*)(g),
      (__attribute__((address_space(3))) void*)(void*)(l),
      16, 0, 0);
}

// ---- pack x|h -> A_bf16 [8192][2048], K-contiguous ----
__global__ __launch_bounds__(256) void pack_a(const float* __restrict__ x,
                                              const float* __restrict__ h,
                                              bf16* __restrict__ A) {
  int idx = blockIdx.x * 256 + threadIdx.x;   // 4,194,304 groups of 4 elems
  int m  = idx >> 9;                          // 512 groups per 2048-row
  int kg = idx & 511;
  int k  = kg * 4;
  const float* src = (k < 1024) ? (x + (size_t)m * 1024 + k)
                                : (h + (size_t)m * 1024 + (k - 1024));
  f32x4 v = *(const f32x4*)src;
  bf16x4 o;
  o[0] = (bf16)v[0]; o[1] = (bf16)v[1]; o[2] = (bf16)v[2]; o[3] = (bf16)v[3];
  *(bf16x4*)(A + (size_t)idx * 4) = o;
}

// ---- pack 8 weight mats -> W_bf16 [4096][2048]; row n = gate*1024 + out_idx ----
__global__ __launch_bounds__(256) void pack_w(
    const float* __restrict__ wxi, const float* __restrict__ whi,
    const float* __restrict__ wxf, const float* __restrict__ whf,
    const float* __restrict__ wxo, const float* __restrict__ who,
    const float* __restrict__ wxg, const float* __restrict__ whg,
    bf16* __restrict__ W) {
  int idx = blockIdx.x * 256 + threadIdx.x;   // 2,097,152 groups of 4
  int n  = idx >> 9;
  int kg = idx & 511;
  int k  = kg * 4;
  int gate = n >> 10;
  int row  = n & 1023;
  const float* wx = (gate == 0) ? wxi : (gate == 1) ? wxf : (gate == 2) ? wxo : wxg;
  const float* wh = (gate == 0) ? whi : (gate == 1) ? whf : (gate == 2) ? who : whg;
  const float* src = (k < 1024) ? (wx + (size_t)row * 1024 + k)
                                : (wh + (size_t)row * 1024 + (k - 1024));
  f32x4 v = *(const f32x4*)src;
  bf16x4 o;
  o[0] = (bf16)v[0]; o[1] = (bf16)v[1]; o[2] = (bf16)v[2]; o[3] = (bf16)v[3];
  *(bf16x4*)(W + (size_t)idx * 4) = o;
}

// ---- bf16 NT GEMM: C[m][n] = sum_k A[m][k] * W[n][k]; Z stored bf16 ----
// m97 structure: 128x128 tile, BK=32, global_load_lds(16B), 4 waves x (4x4) 16x16x32 MFMA.
__global__ __launch_bounds__(256) void gemm_bt(const bf16* __restrict__ A,
                                               const bf16* __restrict__ W,
                                               bf16* __restrict__ Z,
                                               int M, int N, int K) {
  __shared__ __align__(16) bf16 As[BM * BK];   // 8 KB
  __shared__ __align__(16) bf16 Bs[BN * BK];   // 8 KB

  const int t    = threadIdx.x;
  const int wave = t >> 6;
  const int lane = t & 63;
  const int m0 = blockIdx.y * BM;
  const int n0 = blockIdx.x * BN;
  const int wm = (wave >> 1) * 64;   // wave's 64x64 quadrant
  const int wn = (wave & 1) * 64;
  const int lrow = lane & 15;
  const int lkg  = lane >> 4;

  f32x4 acc[4][4] = {};

  // staging: chunk c covers row c>>2, 8 bf16 at col (c&3)*8; LDS offset = c*8 elems
  const int arow = t >> 2;
  const int acol = (t & 3) * 8;
  const bf16* gA0 = A + (size_t)(m0 + arow) * K + acol;
  const bf16* gA1 = A + (size_t)(m0 + 64 + arow) * K + acol;
  const bf16* gB0 = W + (size_t)(n0 + arow) * K + acol;
  const bf16* gB1 = W + (size_t)(n0 + 64 + arow) * K + acol;
  bf16* lA0 = &As[t * 8];
  bf16* lA1 = &As[2048 + t * 8];
  bf16* lB0 = &Bs[t * 8];
  bf16* lB1 = &Bs[2048 + t * 8];

  for (int kt = 0; kt < K; kt += BK) {
    gload_lds16(gA0 + kt, lA0);
    gload_lds16(gA1 + kt, lA1);
    gload_lds16(gB0 + kt, lB0);
    gload_lds16(gB1 + kt, lB1);
    __syncthreads();   // drains vmcnt -> staged data visible

    bf16x8 a[4], b[4];
#pragma unroll
    for (int i = 0; i < 4; ++i) {
      a[i] = *(const bf16x8*)&As[(wm + i * 16 + lrow) * BK + lkg * 8];
      b[i] = *(const bf16x8*)&Bs[(wn + i * 16 + lrow) * BK + lkg * 8];
    }
#pragma unroll
    for (int mi = 0; mi < 4; ++mi)
#pragma unroll
      for (int ni = 0; ni < 4; ++ni)
        acc[mi][ni] = __builtin_amdgcn_mfma_f32_16x16x32_bf16(a[mi], b[ni], acc[mi][ni], 0, 0, 0);
    __syncthreads();   // protect LDS before next stage
  }

  // C/D layout (verified m89/m91): col = lane&15, row = (lane>>4)*4 + reg
  const int crow0 = lkg * 4;
#pragma unroll
  for (int mi = 0; mi < 4; ++mi) {
#pragma unroll
    for (int ni = 0; ni < 4; ++ni) {
      int gm = m0 + wm + mi * 16 + crow0;
      int gn = n0 + wn + ni * 16 + lrow;
#pragma unroll
      for (int r = 0; r < 4; ++r)
        Z[(size_t)(gm + r) * N + gn] = (bf16)acc[mi][ni][r];
    }
  }
}

// ---- LSTM pointwise: gates + biases + c -> h_next, c_next ----
__device__ __forceinline__ float sigf(float v) { return 1.f / (1.f + __expf(-v)); }
__device__ __forceinline__ float tanhfast(float v) {
  v = fminf(15.f, fmaxf(-15.f, v));
  float e = __expf(2.f * v);
  return (e - 1.f) / (e + 1.f);
}

__global__ __launch_bounds__(256) void lstm_pointwise(
    const bf16* __restrict__ Z, const float* __restrict__ c,
    const float* __restrict__ bxi, const float* __restrict__ bhi,
    const float* __restrict__ bxf, const float* __restrict__ bhf,
    const float* __restrict__ bxo, const float* __restrict__ bho,
    const float* __restrict__ bxg, const float* __restrict__ bhg,
    float* __restrict__ out) {
  int idx = blockIdx.x * 256 + threadIdx.x;   // 2,097,152 groups of 4 cols
  int m = idx >> 8;                           // 256 groups per 1024-row
  int j = (idx & 255) * 4;
  size_t zrow = (size_t)m * 4096;

  bf16x4 zi4 = *(const bf16x4*)&Z[zrow + j];
  bf16x4 zf4 = *(const bf16x4*)&Z[zrow + 1024 + j];
  bf16x4 zo4 = *(const bf16x4*)&Z[zrow + 2048 + j];
  bf16x4 zg4 = *(const bf16x4*)&Z[zrow + 3072 + j];
  f32x4 cv = *(const f32x4*)&c[(size_t)m * 1024 + j];

  f32x4 hv, cn;
#pragma unroll
  for (int r = 0; r < 4; ++r) {
    int jj = j + r;
    float zi = (float)zi4[r] + bxi[jj] + bhi[jj];
    float zf = (float)zf4[r] + bxf[jj] + bhf[jj];
    float zo = (float)zo4[r] + bxo[jj] + bho[jj];
    float zg = (float)zg4[r] + bxg[jj] + bhg[jj];
    float it = sigf(zi), ft = sigf(zf), ot = sigf(zo), gt = tanhfast(zg);
    float cnext = ft * cv[r] + it * gt;
    cn[r] = cnext;
    hv[r] = ot * tanhfast(cnext);
  }
  *(f32x4*)&out[(size_t)m * 1024 + j] = hv;                   // h_next
  *(f32x4*)&out[(size_t)8388608 + (size_t)m * 1024 + j] = cn; // c_next
}

extern "C" void kernel_launch(void* const* d_in, const int* in_sizes, int n_in,
                              void* d_out, int out_size, void* d_ws, size_t ws_size,
                              hipStream_t stream) {
  const float* x   = (const float*)d_in[0];
  const float* h   = (const float*)d_in[1];
  const float* c   = (const float*)d_in[2];
  const float* Wxi = (const float*)d_in[3];  const float* bxi = (const float*)d_in[4];
  const float* Whi = (const float*)d_in[5];  const float* bhi = (const float*)d_in[6];
  const float* Wxf = (const float*)d_in[7];  const float* bxf = (const float*)d_in[8];
  const float* Whf = (const float*)d_in[9];  const float* bhf = (const float*)d_in[10];
  const float* Wxo = (const float*)d_in[11]; const float* bxo = (const float*)d_in[12];
  const float* Who = (const float*)d_in[13]; const float* bho = (const float*)d_in[14];
  const float* Wxg = (const float*)d_in[15]; const float* bxg = (const float*)d_in[16];
  const float* Whg = (const float*)d_in[17]; const float* bhg = (const float*)d_in[18];
  float* out = (float*)d_out;

  // workspace: A_bf16 [8192*2048] + W_bf16 [4096*2048] + Z_bf16 [8192*4096] = 112 MB
  bf16* Abuf = (bf16*)d_ws;
  bf16* Wbuf = Abuf + (size_t)8192 * 2048;
  bf16* Zbuf = Wbuf + (size_t)4096 * 2048;

  pack_a<<<16384, 256, 0, stream>>>(x, h, Abuf);
  pack_w<<<8192, 256, 0, stream>>>(Wxi, Whi, Wxf, Whf, Wxo, Who, Wxg, Whg, Wbuf);
  gemm_bt<<<dim3(32, 64), 256, 0, stream>>>(Abuf, Wbuf, Zbuf, 8192, 4096, 2048);
  lstm_pointwise<<<8192, 256, 0, stream>>>(Zbuf, c, bxi, bhi, bxf, bhf, bxo, bho, bxg, bhg, out);
}